// Round 2
// baseline (7059.927 us; speedup 1.0000x reference)
//
#include <hip/hip_runtime.h>
#include <cstdint>
#include <cstddef>

// ---------------- problem constants (fixed by setup_inputs) ----------------
static constexpr int V3   = 100000;
static constexpr int VM   = 25000;
static constexpr int KE   = 128;     // eigenvector count
static constexpr int E3   = 800000;
static constexpr int EM   = 200000;
static constexpr int C3   = 128;
static constexpr int CMID = 256;

#define DEVI __device__ __forceinline__

DEVI float4 ld4(const float* p){ return *(const float4*)p; }
DEVI void   st4(float* p, float4 v){ *(float4*)p = v; }
DEVI float  bf2f(unsigned short u){ return __uint_as_float(((unsigned)u) << 16); }
DEVI unsigned short f2bf(float f){
  unsigned u = __float_as_uint(f);
  u += 0x7FFFu + ((u >> 16) & 1u);   // round to nearest even
  return (unsigned short)(u >> 16);
}

static inline int cdiv(int a, int b){ return (a + b - 1) / b; }

// =====================================================================
// Generic fused row-panel GEMM (f32):
//   OUT[v][:] = act( concat(A0,A1,A2)[v,:] @ W + bias (+ res[v][:]) )
// A0 optionally row-gathered through gidx. BM=64 rows/block, 256 threads.
// IN-PLACE SAFE: OUT may alias A0/A1/A2 because each block reads only rows
// [vbase, vbase+64) of A (all reads complete before the epilogue writes,
// separated by __syncthreads), and writes exactly those rows of OUT.
// =====================================================================
template<int CO, bool RELU, bool RES, bool GATHER>
__global__ __launch_bounds__(256)
void k_gemm(const float* __restrict__ A0, int K0,
            const float* __restrict__ A1, int K1,
            const float* __restrict__ A2, int K2,
            const int* __restrict__ gidx,
            const float* __restrict__ W,
            const float* __restrict__ bias,
            const float* __restrict__ res,
            float* __restrict__ OUT, int V)
{
  static_assert(CO == 128 || CO == 256, "CO");
  constexpr int CG = CO / 8;     // col groups of 8
  constexpr int RT = 256 / CG;   // row-threads (16 or 8)
  constexpr int TV = 64 / RT;    // rows per thread (4 or 8)
  __shared__ float At[16][68];   // A tile transposed [k][v], padded
  __shared__ float Wt[16][CO];

  const int tid = threadIdx.x;
  const int rt  = tid % RT, cg = tid / RT;   // rt fast -> LDS-friendly
  const int v0  = rt * TV, c0 = cg * 8;
  const int vbase = blockIdx.x * 64;
  const int K = K0 + K1 + K2;

  float acc[TV][8];
  #pragma unroll
  for (int i = 0; i < TV; i++)
    #pragma unroll
    for (int j = 0; j < 8; j++) acc[i][j] = 0.f;

  const int vl = tid >> 2, kq = tid & 3;
  const int arow = vbase + vl;
  int srow0 = arow;
  if (GATHER && arow < V) srow0 = gidx[arow];

  for (int kt = 0; kt < K; kt += 16) {
    { // stage A (64 x 16 -> transposed)
      int kg = kt + kq * 4;
      const float* src; int ksz, kl; bool is0;
      if (kg < K0)           { src = A0; ksz = K0; kl = kg;           is0 = true;  }
      else if (kg < K0 + K1) { src = A1; ksz = K1; kl = kg - K0;      is0 = false; }
      else                   { src = A2; ksz = K2; kl = kg - K0 - K1; is0 = false; }
      float4 a = make_float4(0.f, 0.f, 0.f, 0.f);
      if (arow < V) {
        int srow = (GATHER && is0) ? srow0 : arow;
        a = ld4(src + (size_t)srow * ksz + kl);
      }
      At[kq*4+0][vl] = a.x; At[kq*4+1][vl] = a.y;
      At[kq*4+2][vl] = a.z; At[kq*4+3][vl] = a.w;
    }
    { // stage W (16 x CO)
      const float* Wp = W + (size_t)kt * CO;
      #pragma unroll
      for (int i = 0; i < CO / 64; i++) {
        int f  = tid + i * 256;
        int kk = f / (CO / 4);
        int cc = (f % (CO / 4)) * 4;
        st4(&Wt[kk][cc], ld4(Wp + kk * CO + cc));
      }
    }
    __syncthreads();
    #pragma unroll
    for (int kk = 0; kk < 16; kk++) {
      float4 wa = ld4(&Wt[kk][c0]);
      float4 wb = ld4(&Wt[kk][c0 + 4]);
      float av[TV];
      #pragma unroll
      for (int i = 0; i < TV; i += 4) {
        float4 a4 = ld4(&At[kk][v0 + i]);
        av[i] = a4.x; av[i+1] = a4.y; av[i+2] = a4.z; av[i+3] = a4.w;
      }
      #pragma unroll
      for (int i = 0; i < TV; i++) {
        acc[i][0] = fmaf(av[i], wa.x, acc[i][0]);
        acc[i][1] = fmaf(av[i], wa.y, acc[i][1]);
        acc[i][2] = fmaf(av[i], wa.z, acc[i][2]);
        acc[i][3] = fmaf(av[i], wa.w, acc[i][3]);
        acc[i][4] = fmaf(av[i], wb.x, acc[i][4]);
        acc[i][5] = fmaf(av[i], wb.y, acc[i][5]);
        acc[i][6] = fmaf(av[i], wb.z, acc[i][6]);
        acc[i][7] = fmaf(av[i], wb.w, acc[i][7]);
      }
    }
    __syncthreads();
  }

  float bv[8] = {0,0,0,0,0,0,0,0};
  if (bias) {
    float4 ba = ld4(bias + c0), bb = ld4(bias + c0 + 4);
    bv[0]=ba.x; bv[1]=ba.y; bv[2]=ba.z; bv[3]=ba.w;
    bv[4]=bb.x; bv[5]=bb.y; bv[6]=bb.z; bv[7]=bb.w;
  }
  #pragma unroll
  for (int i = 0; i < TV; i++) {
    int row = vbase + v0 + i;
    if (row >= V) continue;
    float o[8];
    #pragma unroll
    for (int j = 0; j < 8; j++) o[j] = acc[i][j] + bv[j];
    if (RES) {
      float4 ra = ld4(res + (size_t)row * CO + c0);
      float4 rb = ld4(res + (size_t)row * CO + c0 + 4);
      o[0]+=ra.x; o[1]+=ra.y; o[2]+=ra.z; o[3]+=ra.w;
      o[4]+=rb.x; o[5]+=rb.y; o[6]+=rb.z; o[7]+=rb.w;
    }
    if (RELU) {
      #pragma unroll
      for (int j = 0; j < 8; j++) o[j] = fmaxf(o[j], 0.f);
    }
    st4(OUT + (size_t)row * CO + c0,     make_float4(o[0],o[1],o[2],o[3]));
    st4(OUT + (size_t)row * CO + c0 + 4, make_float4(o[4],o[5],o[6],o[7]));
  }
}

// =====================================================================
// Fused gate: over A = [GEX | GEY] (bf16, K = 2*KE) accumulate
//   gx = GEX@S, gy = GEY@S, Br = GEX@Tr - GEY@Ti, Bi = GEX@Ti + GEY@Tr
// epilogue: GF = tanh(gx*Br + gy*Bi).  (gX/gY never hit memory.)
// =====================================================================
template<int CO>
__global__ __launch_bounds__(256)
void k_megagate(const unsigned short* __restrict__ GEX,
                const unsigned short* __restrict__ GEY,
                const float* __restrict__ S, const float* __restrict__ Tr,
                const float* __restrict__ Ti,
                float* __restrict__ GF, int V)
{
  constexpr int CG = CO / 8;
  constexpr int RT = 256 / CG;   // 16 or 8
  constexpr int TV = 2;
  constexpr int BM = RT * TV;    // 32 or 16
  __shared__ float At[16][BM + 4];
  __shared__ float Ws[16][CO], Wr[16][CO], Wi[16][CO];

  const int tid = threadIdx.x;
  const int rt  = tid % RT, cg = tid / RT;
  const int v0  = rt * TV, c0 = cg * 8;
  const int vbase = blockIdx.x * BM;

  float gx[TV][8], gy[TV][8], br[TV][8], bi[TV][8];
  #pragma unroll
  for (int i = 0; i < TV; i++)
    #pragma unroll
    for (int j = 0; j < 8; j++) { gx[i][j]=0.f; gy[i][j]=0.f; br[i][j]=0.f; bi[i][j]=0.f; }

  for (int kt = 0; kt < 2 * KE; kt += 16) {
    const bool isX = (kt < KE);
    const int kl0 = isX ? kt : kt - KE;
    const unsigned short* A = isX ? GEX : GEY;
    if (tid < BM * 4) {
      int vl = tid >> 2, kq = tid & 3;
      int row = vbase + vl;
      float4 a = make_float4(0.f,0.f,0.f,0.f);
      if (row < V) {
        ushort4 u = *(const ushort4*)(A + (size_t)row * KE + kl0 + kq * 4);
        a.x = bf2f(u.x); a.y = bf2f(u.y); a.z = bf2f(u.z); a.w = bf2f(u.w);
      }
      At[kq*4+0][vl] = a.x; At[kq*4+1][vl] = a.y;
      At[kq*4+2][vl] = a.z; At[kq*4+3][vl] = a.w;
    }
    {
      #pragma unroll
      for (int i = 0; i < CO / 64; i++) {
        int f  = tid + i * 256;
        int kk = f / (CO / 4);
        int cc = (f % (CO / 4)) * 4;
        size_t o = (size_t)(kl0 + kk) * CO + cc;
        st4(&Ws[kk][cc], ld4(S  + o));
        st4(&Wr[kk][cc], ld4(Tr + o));
        st4(&Wi[kk][cc], ld4(Ti + o));
      }
    }
    __syncthreads();
    #pragma unroll
    for (int kk = 0; kk < 16; kk++) {
      float2 a2 = *(const float2*)&At[kk][v0];
      float a0v = a2.x, a1v = a2.y;
      float4 s0 = ld4(&Ws[kk][c0]), s1 = ld4(&Ws[kk][c0+4]);
      float4 r0 = ld4(&Wr[kk][c0]), r1 = ld4(&Wr[kk][c0+4]);
      float4 t0 = ld4(&Wi[kk][c0]), t1 = ld4(&Wi[kk][c0+4]);
      float sv[8] = {s0.x,s0.y,s0.z,s0.w,s1.x,s1.y,s1.z,s1.w};
      float rv[8] = {r0.x,r0.y,r0.z,r0.w,r1.x,r1.y,r1.z,r1.w};
      float tv[8] = {t0.x,t0.y,t0.z,t0.w,t1.x,t1.y,t1.z,t1.w};
      if (isX) {
        #pragma unroll
        for (int j = 0; j < 8; j++) {
          gx[0][j] = fmaf(a0v, sv[j], gx[0][j]); gx[1][j] = fmaf(a1v, sv[j], gx[1][j]);
          br[0][j] = fmaf(a0v, rv[j], br[0][j]); br[1][j] = fmaf(a1v, rv[j], br[1][j]);
          bi[0][j] = fmaf(a0v, tv[j], bi[0][j]); bi[1][j] = fmaf(a1v, tv[j], bi[1][j]);
        }
      } else {
        #pragma unroll
        for (int j = 0; j < 8; j++) {
          gy[0][j] = fmaf(a0v, sv[j], gy[0][j]); gy[1][j] = fmaf(a1v, sv[j], gy[1][j]);
          br[0][j] = fmaf(-a0v, tv[j], br[0][j]); br[1][j] = fmaf(-a1v, tv[j], br[1][j]);
          bi[0][j] = fmaf(a0v, rv[j], bi[0][j]); bi[1][j] = fmaf(a1v, rv[j], bi[1][j]);
        }
      }
    }
    __syncthreads();
  }
  #pragma unroll
  for (int i = 0; i < TV; i++) {
    int row = vbase + v0 + i;
    if (row >= V) continue;
    float o[8];
    #pragma unroll
    for (int j = 0; j < 8; j++)
      o[j] = tanhf(gx[i][j] * br[i][j] + gy[i][j] * bi[i][j]);
    st4(GF + (size_t)row * CO + c0,     make_float4(o[0],o[1],o[2],o[3]));
    st4(GF + (size_t)row * CO + c0 + 4, make_float4(o[4],o[5],o[6],o[7]));
  }
}

// =====================================================================
// Spectral down-projection: SPEC[k][c] += sum_v E[v][k] * X[v][c] * mass[v]
// (atomic partial sums per v-chunk block)
// =====================================================================
template<int C>
__global__ __launch_bounds__(256)
void k_specdown(const float* __restrict__ X, const float* __restrict__ mass,
                const float* __restrict__ E, float* __restrict__ SPEC,
                int V, int CH)
{
  constexpr int CG   = C / 8;
  constexpr int KTT  = 256 / CG;   // 16 or 8
  constexpr int KEXT = KTT * 8;    // 128 or 64
  __shared__ float xs[8][C];
  __shared__ float es[8][132];

  const int tid = threadIdx.x;
  const int kt = tid % KTT, cg = tid / KTT;
  const int k0 = blockIdx.y * KEXT + kt * 8;
  const int c0 = cg * 8;
  const int vs = blockIdx.x * CH;
  const int ve = min(V, vs + CH);

  float acc[8][8];
  #pragma unroll
  for (int a = 0; a < 8; a++)
    #pragma unroll
    for (int b = 0; b < 8; b++) acc[a][b] = 0.f;

  for (int vb = vs; vb < ve; vb += 8) {
    #pragma unroll
    for (int i = 0; i < C / 128; i++) {   // stage x*mass (8 x C)
      int f = tid + i * 256;
      int r = f / (C / 4), cc = (f % (C / 4)) * 4;
      int v = vb + r;
      float4 xv = make_float4(0.f,0.f,0.f,0.f);
      if (v < ve) {
        xv = ld4(X + (size_t)v * C + cc);
        float m = mass[v];
        xv.x *= m; xv.y *= m; xv.z *= m; xv.w *= m;
      }
      st4(&xs[r][cc], xv);
    }
    { // stage e (8 x 128)
      int r = tid >> 5, cc = (tid & 31) * 4;
      int v = vb + r;
      float4 ev = make_float4(0.f,0.f,0.f,0.f);
      if (v < ve) ev = ld4(E + (size_t)v * KE + cc);
      st4(&es[r][cc], ev);
    }
    __syncthreads();
    #pragma unroll
    for (int r = 0; r < 8; r++) {
      float4 e0 = ld4(&es[r][k0]), e1 = ld4(&es[r][k0 + 4]);
      float4 x0 = ld4(&xs[r][c0]), x1 = ld4(&xs[r][c0 + 4]);
      float evv[8] = {e0.x,e0.y,e0.z,e0.w,e1.x,e1.y,e1.z,e1.w};
      float xvv[8] = {x0.x,x0.y,x0.z,x0.w,x1.x,x1.y,x1.z,x1.w};
      #pragma unroll
      for (int a = 0; a < 8; a++)
        #pragma unroll
        for (int b = 0; b < 8; b++)
          acc[a][b] = fmaf(evv[a], xvv[b], acc[a][b]);
    }
    __syncthreads();
  }
  #pragma unroll
  for (int a = 0; a < 8; a++)
    #pragma unroll
    for (int b = 0; b < 8; b++)
      unsafeAtomicAdd(&SPEC[(size_t)(k0 + a) * C + c0 + b], acc[a][b]);
}

// S = exp(-evals*max(dt,1e-8)) * SPEC ;  Tr = S@Are ; Ti = S@Aim
template<int C>
__global__ void k_smallprep(const float* __restrict__ SPEC, const float* __restrict__ evals,
                            const float* __restrict__ dt,
                            const float* __restrict__ Are, const float* __restrict__ Aim,
                            float* __restrict__ S, float* __restrict__ Tr, float* __restrict__ Ti)
{
  __shared__ float sld[C];
  const int k = blockIdx.x;
  const int c = threadIdx.x;
  const float ev = evals[k];
  float s = expf(-ev * fmaxf(dt[c], 1e-8f)) * SPEC[(size_t)k * C + c];
  S[(size_t)k * C + c] = s;
  sld[c] = s;
  __syncthreads();
  float tr = 0.f, ti = 0.f;
  for (int j = 0; j < C; j++) {
    float sj = sld[j];
    tr = fmaf(sj, Are[(size_t)j * C + c], tr);
    ti = fmaf(sj, Aim[(size_t)j * C + c], ti);
  }
  Tr[(size_t)k * C + c] = tr;
  Ti[(size_t)k * C + c] = ti;
}

// ============================ CSR build ==============================
__global__ void k_hist(const int* __restrict__ idx, int* __restrict__ deg, int E) {
  int e = blockIdx.x * 256 + threadIdx.x;
  if (e < E) atomicAdd(&deg[idx[2 * e]], 1);
}
__global__ void k_scan1(const int* __restrict__ deg, int* __restrict__ excl,
                        int* __restrict__ bsum, int V) {
  __shared__ int sd[256];
  int t = threadIdx.x;
  int i = blockIdx.x * 256 + t;
  int v = (i < V) ? deg[i] : 0;
  sd[t] = v;
  __syncthreads();
  for (int off = 1; off < 256; off <<= 1) {
    int add = (t >= off) ? sd[t - off] : 0;
    __syncthreads();
    sd[t] += add;
    __syncthreads();
  }
  if (i < V) excl[i] = sd[t] - v;
  if (t == 255) bsum[blockIdx.x] = sd[255];
}
__global__ void k_scan2(int* __restrict__ bsum, int nb, int* __restrict__ rowptr, int V) {
  __shared__ int sd[512];
  int t = threadIdx.x;
  int v = (t < nb) ? bsum[t] : 0;
  sd[t] = v;
  __syncthreads();
  for (int off = 1; off < 512; off <<= 1) {
    int add = (t >= off) ? sd[t - off] : 0;
    __syncthreads();
    sd[t] += add;
    __syncthreads();
  }
  if (t < nb) bsum[t] = sd[t] - v;
  if (t == 0) rowptr[V] = sd[511];
}
__global__ void k_scan3(const int* __restrict__ excl, const int* __restrict__ bsum,
                        int* __restrict__ rowptr, int V) {
  int i = blockIdx.x * 256 + threadIdx.x;
  if (i < V) rowptr[i] = excl[i] + bsum[i >> 8];
}
__global__ void k_scatter(const int* __restrict__ idx, const float* __restrict__ val,
                          const int* __restrict__ rowptr, int* __restrict__ cur,
                          int* __restrict__ ecol, float* __restrict__ eval, int E) {
  int e = blockIdx.x * 256 + threadIdx.x;
  if (e < E) {
    int d = idx[2 * e];
    int p = rowptr[d] + atomicAdd(&cur[d], 1);
    ecol[p] = idx[2 * e + 1];
    eval[p] = val[e];
  }
}
// GE[r][:] = sum_{edges of r} val * E[col][:]  -> bf16 output
__global__ __launch_bounds__(256)
void k_spmm_csr(const int* __restrict__ rowptr, const int* __restrict__ ecol,
                const float* __restrict__ eval, const float* __restrict__ E,
                unsigned short* __restrict__ GE, int V) {
  int r = blockIdx.x * 8 + (threadIdx.x >> 5);
  int lane = threadIdx.x & 31;
  if (r >= V) return;
  int j1 = rowptr[r + 1];
  float4 a = make_float4(0.f,0.f,0.f,0.f);
  for (int j = rowptr[r]; j < j1; j++) {
    int c = ecol[j];
    float v = eval[j];
    float4 x = ld4(E + (size_t)c * KE + lane * 4);
    a.x = fmaf(v, x.x, a.x); a.y = fmaf(v, x.y, a.y);
    a.z = fmaf(v, x.z, a.z); a.w = fmaf(v, x.w, a.w);
  }
  ushort4 o;
  o.x = f2bf(a.x); o.y = f2bf(a.y); o.z = f2bf(a.z); o.w = f2bf(a.w);
  *(ushort4*)(GE + (size_t)r * KE + lane * 4) = o;
}

// ============================ segment max ============================
__global__ void k_segmax_init(unsigned* __restrict__ u, int n) {
  int i = blockIdx.x * 256 + threadIdx.x;
  if (i < n) u[i] = 0x007FFFFFu;   // encode(-inf)
}
__global__ void k_segmax_scatter(const float* __restrict__ X, const int* __restrict__ tr,
                                 unsigned* __restrict__ u) {
  int i = blockIdx.x * 256 + threadIdx.x;
  if (i >= V3 * C3) return;
  int v = i >> 7, c = i & 127;
  unsigned b = __float_as_uint(X[i]);
  unsigned m = (b & 0x80000000u) ? ~b : (b | 0x80000000u);
  atomicMax(&u[((size_t)tr[v] << 7) + c], m);
}
__global__ void k_segmax_decode(const unsigned* __restrict__ u, float* __restrict__ out, int n) {
  int i = blockIdx.x * 256 + threadIdx.x;
  if (i < n) {
    unsigned m = u[i];
    float f = 0.f;
    if (m != 0x007FFFFFu) {
      unsigned b = (m & 0x80000000u) ? (m & 0x7FFFFFFFu) : ~m;
      f = __uint_as_float(b);
    }
    out[i] = f;
  }
}

// ========================= final projection ==========================
__global__ __launch_bounds__(256)
void k_outproj(const float* __restrict__ Y, const float* __restrict__ W,
               const float* __restrict__ B, float* __restrict__ OUT, int V) {
  __shared__ float Wl[128][22];
  __shared__ float ys[8][128];
  const int tid = threadIdx.x;
  for (int f = tid; f < 128 * 21; f += 256) Wl[f / 21][f % 21] = W[f];
  {
    int r = tid >> 5, cc = (tid & 31) * 4;
    int v = blockIdx.x * 8 + r;
    float4 yv = make_float4(0.f,0.f,0.f,0.f);
    if (v < V) yv = ld4(Y + (size_t)v * C3 + cc);
    st4(&ys[r][cc], yv);
  }
  __syncthreads();
  int r = tid >> 5, c = tid & 31;
  int v = blockIdx.x * 8 + r;
  if (v < V && c < 21) {
    float acc = B[c];
    #pragma unroll 8
    for (int k = 0; k < 128; k++) acc = fmaf(ys[r][k], Wl[k][c], acc);
    OUT[(size_t)v * 21 + c] = acc;
  }
}

// =====================================================================
extern "C" void kernel_launch(void* const* d_in, const int* in_sizes, int n_in,
                              void* d_out, int out_size, void* d_ws, size_t ws_size,
                              hipStream_t stream)
{
  (void)in_sizes; (void)n_in; (void)out_size;
  const float* x_in    = (const float*)d_in[0];
  const float* mass3   = (const float*)d_in[1];
  const float* evals3  = (const float*)d_in[2];
  const float* evecs3  = (const float*)d_in[3];
  const int*   gX3i    = (const int*)d_in[4];
  const float* gX3v    = (const float*)d_in[5];
  const int*   gY3i    = (const int*)d_in[6];
  const float* gY3v    = (const float*)d_in[7];
  const float* massm   = (const float*)d_in[8];
  const float* evalsm  = (const float*)d_in[9];
  const float* evecsm  = (const float*)d_in[10];
  const int*   gXmi    = (const int*)d_in[11];
  const float* gXmv    = (const float*)d_in[12];
  const int*   gYmi    = (const int*)d_in[13];
  const float* gYmv    = (const float*)d_in[14];
  const int*   tr34    = (const int*)d_in[15];
  const float* in_w    = (const float*)d_in[16];
  const float* in_b    = (const float*)d_in[17];
  const float* widen_w = (const float*)d_in[18];
  const float* widen_b = (const float*)d_in[19];
  const float* narrow_w= (const float*)d_in[20];
  const float* narrow_b= (const float*)d_in[21];
  const float* halve_w = (const float*)d_in[22];
  const float* halve_b = (const float*)d_in[23];
  const float* out_w   = (const float*)d_in[24];
  const float* out_b   = (const float*)d_in[25];
  const float* enc_p[9]; const float* mid_p[9]; const float* dec_p[9];
  for (int i = 0; i < 9; i++) {
    enc_p[i] = (const float*)d_in[26 + i];
    mid_p[i] = (const float*)d_in[35 + i];
    dec_p[i] = (const float*)d_in[44 + i];
  }

  // ---------------- workspace layout (compact, ~218.2 MB) ----------------
  // [S0 | S1 | S2] three V3x128 f32 rotation slots (51.2 MB each)
  // [GEX3|GEY3] bf16 V3x128 (25.6 MB each)  [GEXm|GEYm] bf16 VMx128 (6.4 MB each)
  // [spec|Smat|Trm|Tim|bsum] smalls
  // CSR scratch lives inside S0 (only used before in_proj).
  // Mid-stage slots m0..m3 (VMx256 f32, 25.6 MB) overlay S0/S2 while S1
  // holds x3.  xm_u/xm_dec overlay m3.
  char* ws = (char*)d_ws;
  const size_t B3 = (size_t)V3 * C3 * 4;           // 51,200,000
  const size_t GE3B = (size_t)V3 * KE * 2;         // 25,600,000
  const size_t GEMB = (size_t)VM * KE * 2;         //  6,400,000
  const size_t NEED = 3 * B3 + 2 * GE3B + 2 * GEMB + 4 * 131072 + 4096;
  if (ws_size < NEED) return;   // diagnostic: clean absmax failure, no fault

  float* S0 = (float*)(ws);
  float* S1 = (float*)(ws + B3);
  float* S2 = (float*)(ws + 2 * B3);
  unsigned short* GEX3 = (unsigned short*)(ws + 3 * B3);
  unsigned short* GEY3 = (unsigned short*)(ws + 3 * B3 + GE3B);
  unsigned short* GEXm = (unsigned short*)(ws + 3 * B3 + 2 * GE3B);
  unsigned short* GEYm = (unsigned short*)(ws + 3 * B3 + 2 * GE3B + GEMB);
  char* smallb = ws + 3 * B3 + 2 * GE3B + 2 * GEMB;
  float* spec = (float*)(smallb);
  float* Smat = (float*)(smallb + 131072);
  float* Trm  = (float*)(smallb + 2 * 131072);
  float* Tim  = (float*)(smallb + 3 * 131072);
  int*   bsum = (int*)(smallb + 4 * 131072);       // <=512 ints

  // CSR scratch (inside S0; dead after GE builds)
  int*   rowptr = (int*)S0;                        // (V3+1) ints -> 400,128 B
  int*   deg    = (int*)((char*)S0 + 400128);      // V3 ints
  int*   ecol   = (int*)((char*)S0 + 800256);      // E3 ints (also scan scratch)
  float* evalv  = (float*)((char*)S0 + 4000256);   // E3 floats

  // mid-stage overlay (S1 holds x3 during this phase)
  float* m0 = S0;                                  // VM*256 f32
  float* m1 = (float*)(ws + 25600000);
  float* m2 = S2;
  unsigned* xm_u = (unsigned*)(ws + 2 * B3 + 25600000);        // VM*128 u32
  float* xm_dec  = (float*)(ws + 2 * B3 + 25600000 + 12800000);// VM*128 f32

  // ---- precompute GE = G @ evecs for the 4 graphs (CSR build + spmm) ----
  auto build_ge = [&](const int* idx, const float* val, int E_, int V_,
                      const float* Evec, unsigned short* GE) {
    hipMemsetAsync(deg, 0, (size_t)V_ * 4, stream);
    k_hist<<<cdiv(E_, 256), 256, 0, stream>>>(idx, deg, E_);
    int nb = cdiv(V_, 256);
    k_scan1<<<nb, 256, 0, stream>>>(deg, ecol, bsum, V_);
    k_scan2<<<1, 512, 0, stream>>>(bsum, nb, rowptr, V_);
    k_scan3<<<nb, 256, 0, stream>>>(ecol, bsum, rowptr, V_);
    hipMemsetAsync(deg, 0, (size_t)V_ * 4, stream);
    k_scatter<<<cdiv(E_, 256), 256, 0, stream>>>(idx, val, rowptr, deg, ecol, evalv, E_);
    k_spmm_csr<<<cdiv(V_, 8), 256, 0, stream>>>(rowptr, ecol, evalv, Evec, GE, V_);
  };
  build_ge(gX3i, gX3v, E3, V3, evecs3, GEX3);
  build_ge(gY3i, gY3v, E3, V3, evecs3, GEY3);
  build_ge(gXmi, gXmv, EM, VM, evecsm, GEXm);
  build_ge(gYmi, gYmv, EM, VM, evecsm, GEYm);

  // ---- block runners (3-slot: in=X, scratch sx, sg; out = sg) ----
  auto run_block3 = [&](const float* X, float* sx, float* sg, const float* p[9], int i) -> float* {
    const float* dt  = p[0] + (size_t)i * C3;
    const float* Are = p[1] + (size_t)i * C3 * C3;
    const float* Aim = p[2] + (size_t)i * C3 * C3;
    const float* w0  = p[3] + (size_t)i * 3 * C3 * C3;
    const float* b0  = p[4] + (size_t)i * C3;
    const float* w1  = p[5] + (size_t)i * C3 * C3;
    const float* b1  = p[6] + (size_t)i * C3;
    const float* w2  = p[7] + (size_t)i * C3 * C3;
    const float* b2  = p[8] + (size_t)i * C3;
    hipMemsetAsync(spec, 0, (size_t)KE * C3 * 4, stream);
    k_specdown<C3><<<dim3(cdiv(V3, 256), 1), 256, 0, stream>>>(X, mass3, evecs3, spec, V3, 256);
    k_smallprep<C3><<<KE, C3, 0, stream>>>(spec, evals3, dt, Are, Aim, Smat, Trm, Tim);
    k_gemm<C3,false,false,false><<<cdiv(V3,64), 256, 0, stream>>>(
        evecs3, KE, nullptr, 0, nullptr, 0, nullptr, Smat, nullptr, nullptr, sx, V3);
    k_megagate<C3><<<cdiv(V3,32), 256, 0, stream>>>(GEX3, GEY3, Smat, Trm, Tim, sg, V3);
    k_gemm<C3,true,false,false><<<cdiv(V3,64), 256, 0, stream>>>(
        X, C3, sx, C3, sg, C3, nullptr, w0, b0, nullptr, sg, V3);   // in-place on A2
    k_gemm<C3,true,false,false><<<cdiv(V3,64), 256, 0, stream>>>(
        sg, C3, nullptr, 0, nullptr, 0, nullptr, w1, b1, nullptr, sx, V3);
    k_gemm<C3,false,true,false><<<cdiv(V3,64), 256, 0, stream>>>(
        sx, C3, nullptr, 0, nullptr, 0, nullptr, w2, b2, X, sg, V3);
    return sg;
  };
  auto run_blockm = [&](const float* X, float* sx, float* sg, const float* p[9], int i) -> float* {
    const float* dt  = p[0] + (size_t)i * CMID;
    const float* Are = p[1] + (size_t)i * CMID * CMID;
    const float* Aim = p[2] + (size_t)i * CMID * CMID;
    const float* w0  = p[3] + (size_t)i * 3 * CMID * CMID;
    const float* b0  = p[4] + (size_t)i * CMID;
    const float* w1  = p[5] + (size_t)i * CMID * CMID;
    const float* b1  = p[6] + (size_t)i * CMID;
    const float* w2  = p[7] + (size_t)i * CMID * CMID;
    const float* b2  = p[8] + (size_t)i * CMID;
    hipMemsetAsync(spec, 0, (size_t)KE * CMID * 4, stream);
    k_specdown<CMID><<<dim3(cdiv(VM, 128), 2), 256, 0, stream>>>(X, massm, evecsm, spec, VM, 128);
    k_smallprep<CMID><<<KE, CMID, 0, stream>>>(spec, evalsm, dt, Are, Aim, Smat, Trm, Tim);
    k_gemm<CMID,false,false,false><<<cdiv(VM,64), 256, 0, stream>>>(
        evecsm, KE, nullptr, 0, nullptr, 0, nullptr, Smat, nullptr, nullptr, sx, VM);
    k_megagate<CMID><<<cdiv(VM,16), 256, 0, stream>>>(GEXm, GEYm, Smat, Trm, Tim, sg, VM);
    k_gemm<CMID,true,false,false><<<cdiv(VM,64), 256, 0, stream>>>(
        X, CMID, sx, CMID, sg, CMID, nullptr, w0, b0, nullptr, sg, VM); // in-place on A2
    k_gemm<CMID,true,false,false><<<cdiv(VM,64), 256, 0, stream>>>(
        sg, CMID, nullptr, 0, nullptr, 0, nullptr, w1, b1, nullptr, sx, VM);
    k_gemm<CMID,false,true,false><<<cdiv(VM,64), 256, 0, stream>>>(
        sx, CMID, nullptr, 0, nullptr, 0, nullptr, w2, b2, X, sg, VM);
    return sg;
  };

  // ---- encoder ----
  k_gemm<C3,true,false,false><<<cdiv(V3,64), 256, 0, stream>>>(
      x_in, 16, nullptr, 0, nullptr, 0, nullptr, in_w, in_b, nullptr, S0, V3);
  run_block3(S0, S1, S2, enc_p, 0);   // out S2
  run_block3(S2, S0, S1, enc_p, 1);   // out S1 = x3  (S0, S2 now free)

  // ---- pool to medium mesh ----
  k_segmax_init<<<cdiv(VM * C3, 256), 256, 0, stream>>>(xm_u, VM * C3);
  k_segmax_scatter<<<cdiv(V3 * C3, 256), 256, 0, stream>>>(S1, tr34, xm_u);
  k_segmax_decode<<<cdiv(VM * C3, 256), 256, 0, stream>>>(xm_u, xm_dec, VM * C3);
  k_gemm<CMID,true,false,false><<<cdiv(VM,64), 256, 0, stream>>>(
      xm_dec, C3, nullptr, 0, nullptr, 0, nullptr, widen_w, widen_b, nullptr, m0, VM);
  run_blockm(m0, m1, m2, mid_p, 0);   // out m2
  run_blockm(m2, m0, m1, mid_p, 1);   // out m1 = xm_final (in S0 upper half)

  // ---- unpool: gather + narrow (writes all of S2; m1 in S0 untouched) ----
  k_gemm<C3,true,false,true><<<cdiv(V3,64), 256, 0, stream>>>(
      m1, CMID, nullptr, 0, nullptr, 0, tr34, narrow_w, narrow_b, nullptr, S2, V3);
  // halve on concat([y_narrow, x3]) -> S0 (m0/m1 dead now)
  k_gemm<C3,true,false,false><<<cdiv(V3,64), 256, 0, stream>>>(
      S2, C3, S1, C3, nullptr, 0, nullptr, halve_w, halve_b, nullptr, S0, V3);

  // ---- decoder ----
  run_block3(S0, S1, S2, dec_p, 0);   // out S2 (x3 in S1 dead, used as scratch)
  run_block3(S2, S0, S1, dec_p, 1);   // out S1

  // ---- output projection ----
  k_outproj<<<cdiv(V3, 8), 256, 0, stream>>>(S1, out_w, out_b, (float*)d_out, V3);
}

// Round 3
// 2211.244 us; speedup vs baseline: 3.1927x; 3.1927x over previous
//
#include <hip/hip_runtime.h>
#include <cstdint>
#include <cstddef>

// ---------------- problem constants (fixed by setup_inputs) ----------------
static constexpr int V3   = 100000;
static constexpr int VM   = 25000;
static constexpr int KE   = 128;
static constexpr int E3   = 800000;
static constexpr int EM   = 200000;
static constexpr int C3   = 128;
static constexpr int CMID = 256;

typedef unsigned short u16;
typedef unsigned int   u32;
using short8v = __attribute__((ext_vector_type(8))) short;
using f32x4   = __attribute__((ext_vector_type(4))) float;

#define DEVI __device__ __forceinline__
DEVI float4 ld4(const float* p){ return *(const float4*)p; }
DEVI void   st4(float* p, float4 v){ *(float4*)p = v; }
DEVI float  bf2f(u16 u){ return __uint_as_float(((u32)u) << 16); }
DEVI u16    f2bf(float f){
  u32 u = __float_as_uint(f);
  u += 0x7FFFu + ((u >> 16) & 1u);   // RNE
  return (u16)(u >> 16);
}
DEVI u32 pk2(float a, float b){ return (u32)f2bf(a) | ((u32)f2bf(b) << 16); }

static inline int cdiv(int a, int b){ return (a + b - 1) / b; }

// =====================================================================
// MFMA GEMM: OUT[v][:] = act( concat(A0,A1,A2)[v,:] @ W + bias (+res) )
// A sources f32 (aty=0) or bf16 (aty=1); W pre-transposed bf16 Wt[n][k]
// (per-source base/ldK/koff). BM=64, BN=128 window (blockIdx.y), 4 waves.
// In-place OUT over a row-aligned A source is safe ONLY when gridDim.y==1.
// =====================================================================
template<bool RELU, bool RES, bool GATHER, bool OBF16>
__global__ __launch_bounds__(256)
void k_mgemm(const void* __restrict__ A0, int aty0, int K0,
             const u16* __restrict__ wt0, int wl0, int wo0,
             const void* __restrict__ A1, int aty1, int K1,
             const u16* __restrict__ wt1, int wl1, int wo1,
             const void* __restrict__ A2, int aty2, int K2,
             const u16* __restrict__ wt2, int wl2, int wo2,
             const int* __restrict__ gidx,
             const float* __restrict__ bias, const float* __restrict__ res,
             void* __restrict__ OUT, int CO, int V)
{
  __shared__ __align__(16) u16 As[64 * 40];   // [row][32k], 80B rows (16B pad)
  __shared__ __align__(16) u16 Ws[128 * 40];  // [col][32k]

  const int tid  = threadIdx.x;
  const int wave = tid >> 6, lane = tid & 63;
  const int vbase = blockIdx.x * 64;
  const int ncol0 = blockIdx.y * 128;
  const int KT = K0 + K1 + K2;

  f32x4 acc[8];
  #pragma unroll
  for (int n = 0; n < 8; n++) { acc[n][0]=0.f; acc[n][1]=0.f; acc[n][2]=0.f; acc[n][3]=0.f; }

  const int ar = tid >> 2, ac = tid & 3;
  const int arow = vbase + ar;
  int grow0 = arow;
  if (GATHER && arow < V) grow0 = gidx[arow];

  for (int kt = 0; kt < KT; kt += 32) {
    { // ---- A stage: 64x32 -> bf16 LDS ----
      int kg = kt + ac * 8;
      uint4 aw = make_uint4(0,0,0,0);
      if (arow < V && kg < KT) {
        const void* src; int aty, koff, sK; bool s0;
        if (kg < K0)            { src=A0; aty=aty0; koff=0;     sK=K0; s0=true;  }
        else if (kg < K0 + K1)  { src=A1; aty=aty1; koff=K0;    sK=K1; s0=false; }
        else                    { src=A2; aty=aty2; koff=K0+K1; sK=K2; s0=false; }
        int row = (GATHER && s0) ? grow0 : arow;
        int kl = kg - koff;
        if (aty) {
          aw = *(const uint4*)((const u16*)src + (size_t)row * sK + kl);
        } else {
          const float* fp = (const float*)src + (size_t)row * sK + kl;
          float4 x = ld4(fp), y = ld4(fp + 4);
          aw = make_uint4(pk2(x.x,x.y), pk2(x.z,x.w), pk2(y.x,y.y), pk2(y.z,y.w));
        }
      }
      *(uint4*)&As[ar * 40 + ac * 8] = aw;
    }
    // ---- W stage: 128 cols x 32k from pre-transposed bf16 ----
    #pragma unroll
    for (int i = 0; i < 2; i++) {
      int col = tid & 127;
      int c = (tid >> 7) + 2 * i;
      int kg = kt + c * 8;
      uint4 ww = make_uint4(0,0,0,0);
      if (kg < KT) {
        const u16* wt; int koff, wl, wo;
        if (kg < K0)           { wt=wt0; koff=0;     wl=wl0; wo=wo0; }
        else if (kg < K0+K1)   { wt=wt1; koff=K0;    wl=wl1; wo=wo1; }
        else                   { wt=wt2; koff=K0+K1; wl=wl2; wo=wo2; }
        ww = *(const uint4*)(wt + (size_t)(ncol0 + col) * wl + wo + (kg - koff));
      }
      *(uint4*)&Ws[col * 40 + c * 8] = ww;
    }
    __syncthreads();
    {
      const int mrow = (wave << 4) + (lane & 15);
      const int kc = lane >> 4;
      short8v a = *(const short8v*)(const void*)&As[mrow * 40 + kc * 8];
      #pragma unroll
      for (int n = 0; n < 8; n++) {
        short8v b = *(const short8v*)(const void*)&Ws[(n * 16 + (lane & 15)) * 40 + kc * 8];
        acc[n] = __builtin_amdgcn_mfma_f32_16x16x32_bf16(a, b, acc[n], 0, 0, 0);
      }
    }
    __syncthreads();
  }

  // ---- epilogue ----
  const int q4 = (lane >> 4) * 4, colb = lane & 15;
  #pragma unroll
  for (int n = 0; n < 8; n++) {
    int gcol = ncol0 + n * 16 + colb;
    float bv = bias ? bias[gcol] : 0.f;
    #pragma unroll
    for (int q = 0; q < 4; q++) {
      int grow = vbase + (wave << 4) + q4 + q;
      if (grow >= V) continue;
      float o = acc[n][q] + bv;
      if (RES) o += res[(size_t)grow * CO + gcol];
      if (RELU) o = fmaxf(o, 0.f);
      if (OBF16) ((u16*)OUT)[(size_t)grow * CO + gcol] = f2bf(o);
      else       ((float*)OUT)[(size_t)grow * CO + gcol] = o;
    }
  }
}

// =====================================================================
// MFMA megagate: A = GEX/GEY (bf16 [V][128]); weights St/Trt/Tit bf16
// transposed [CO][128]. gx=GEX@S gy=GEY@S br=GEX@Tr-GEY@Ti bi=GEX@Ti+GEY@Tr
// GF = tanh(gx*br+gy*bi) -> bf16. BM=64, BN=64 window (blockIdx.y).
// =====================================================================
__global__ __launch_bounds__(256)
void k_mgate(const u16* __restrict__ GEX, const u16* __restrict__ GEY,
             const u16* __restrict__ St, const u16* __restrict__ Trt,
             const u16* __restrict__ Tit,
             u16* __restrict__ GF, int CO, int V)
{
  __shared__ __align__(16) u16 Ax[64*40], Ay[64*40], An[64*40];
  __shared__ __align__(16) u16 Bs[64*40], Br_[64*40], Bi_[64*40];

  const int tid = threadIdx.x;
  const int wave = tid >> 6, lane = tid & 63;
  const int vbase = blockIdx.x * 64;
  const int ncol0 = blockIdx.y * 64;

  f32x4 gx[4], gy[4], br[4], bi[4];
  #pragma unroll
  for (int n = 0; n < 4; n++)
    #pragma unroll
    for (int q = 0; q < 4; q++) { gx[n][q]=0.f; gy[n][q]=0.f; br[n][q]=0.f; bi[n][q]=0.f; }

  const int ar = tid >> 2, ac = tid & 3;
  const int arow = vbase + ar;

  for (int kt = 0; kt < KE; kt += 32) {
    {
      uint4 zx = make_uint4(0,0,0,0), zy = make_uint4(0,0,0,0);
      if (arow < V) {
        zx = *(const uint4*)(GEX + (size_t)arow * KE + kt + ac * 8);
        zy = *(const uint4*)(GEY + (size_t)arow * KE + kt + ac * 8);
      }
      uint4 zn = make_uint4(zy.x ^ 0x80008000u, zy.y ^ 0x80008000u,
                            zy.z ^ 0x80008000u, zy.w ^ 0x80008000u);
      *(uint4*)&Ax[ar*40 + ac*8] = zx;
      *(uint4*)&Ay[ar*40 + ac*8] = zy;
      *(uint4*)&An[ar*40 + ac*8] = zn;
    }
    {
      int col = tid & 63, c = tid >> 6;
      size_t wo = (size_t)(ncol0 + col) * KE + kt + c * 8;
      *(uint4*)&Bs[col*40 + c*8]  = *(const uint4*)(St  + wo);
      *(uint4*)&Br_[col*40 + c*8] = *(const uint4*)(Trt + wo);
      *(uint4*)&Bi_[col*40 + c*8] = *(const uint4*)(Tit + wo);
    }
    __syncthreads();
    {
      const int mrow = (wave << 4) + (lane & 15);
      const int kc = lane >> 4;
      short8v ax = *(const short8v*)(const void*)&Ax[mrow*40 + kc*8];
      short8v ay = *(const short8v*)(const void*)&Ay[mrow*40 + kc*8];
      short8v an = *(const short8v*)(const void*)&An[mrow*40 + kc*8];
      #pragma unroll
      for (int n = 0; n < 4; n++) {
        int bofs = (n * 16 + (lane & 15)) * 40 + kc * 8;
        short8v bs = *(const short8v*)(const void*)&Bs[bofs];
        short8v brv = *(const short8v*)(const void*)&Br_[bofs];
        short8v biv = *(const short8v*)(const void*)&Bi_[bofs];
        gx[n] = __builtin_amdgcn_mfma_f32_16x16x32_bf16(ax, bs,  gx[n], 0,0,0);
        gy[n] = __builtin_amdgcn_mfma_f32_16x16x32_bf16(ay, bs,  gy[n], 0,0,0);
        br[n] = __builtin_amdgcn_mfma_f32_16x16x32_bf16(ax, brv, br[n], 0,0,0);
        br[n] = __builtin_amdgcn_mfma_f32_16x16x32_bf16(an, biv, br[n], 0,0,0);
        bi[n] = __builtin_amdgcn_mfma_f32_16x16x32_bf16(ax, biv, bi[n], 0,0,0);
        bi[n] = __builtin_amdgcn_mfma_f32_16x16x32_bf16(ay, brv, bi[n], 0,0,0);
      }
    }
    __syncthreads();
  }

  const int q4 = (lane >> 4) * 4, colb = lane & 15;
  #pragma unroll
  for (int n = 0; n < 4; n++) {
    int gcol = ncol0 + n * 16 + colb;
    #pragma unroll
    for (int q = 0; q < 4; q++) {
      int grow = vbase + (wave << 4) + q4 + q;
      if (grow >= V) continue;
      float o = tanhf(gx[n][q] * br[n][q] + gy[n][q] * bi[n][q]);
      GF[(size_t)grow * CO + gcol] = f2bf(o);
    }
  }
}

// =====================================================================
// MFMA spectral down-projection: SPEC[ke][c] += sum_v E[v][ke]*X[v][c]*m[v]
// A = E^T (staged transposed), B = X*mass. Split-K + f32 atomics.
// grid: x = K-chunks (CH), y = m-half (64), z = col-window (128)
// =====================================================================
__global__ __launch_bounds__(256)
void k_specmm(const float* __restrict__ E, const float* __restrict__ X,
              const float* __restrict__ mass, float* __restrict__ SPEC,
              int C, int V, int CH)
{
  __shared__ __align__(16) u16 As[64*40];
  __shared__ __align__(16) u16 Bs[128*40];

  const int tid = threadIdx.x;
  const int wave = tid >> 6, lane = tid & 63;
  const int m0 = blockIdx.y * 64;
  const int n0 = blockIdx.z * 128;
  const int vs = blockIdx.x * CH;
  const int ve = min(V, vs + CH);

  f32x4 acc[8];
  #pragma unroll
  for (int n = 0; n < 8; n++) { acc[n][0]=0.f; acc[n][1]=0.f; acc[n][2]=0.f; acc[n][3]=0.f; }

  for (int kt = vs; kt < ve; kt += 32) {
    { // A: As[m][k] = E[kt+k][m0+m]
      int m = tid & 63, c = tid >> 6;
      float f[8];
      #pragma unroll
      for (int j = 0; j < 8; j++) {
        int v = kt + c * 8 + j;
        f[j] = (v < ve) ? E[(size_t)v * KE + m0 + m] : 0.f;
      }
      *(uint4*)&As[m*40 + c*8] =
        make_uint4(pk2(f[0],f[1]), pk2(f[2],f[3]), pk2(f[4],f[5]), pk2(f[6],f[7]));
    }
    #pragma unroll
    for (int i = 0; i < 2; i++) { // B: Bs[col][k] = X[kt+k][n0+col]*mass
      int col = tid & 127, c = (tid >> 7) + 2 * i;
      float f[8];
      #pragma unroll
      for (int j = 0; j < 8; j++) {
        int v = kt + c * 8 + j;
        f[j] = (v < ve) ? X[(size_t)v * C + n0 + col] * mass[v] : 0.f;
      }
      *(uint4*)&Bs[col*40 + c*8] =
        make_uint4(pk2(f[0],f[1]), pk2(f[2],f[3]), pk2(f[4],f[5]), pk2(f[6],f[7]));
    }
    __syncthreads();
    {
      const int mrow = (wave << 4) + (lane & 15);
      const int kc = lane >> 4;
      short8v a = *(const short8v*)(const void*)&As[mrow*40 + kc*8];
      #pragma unroll
      for (int n = 0; n < 8; n++) {
        short8v b = *(const short8v*)(const void*)&Bs[(n*16 + (lane & 15))*40 + kc*8];
        acc[n] = __builtin_amdgcn_mfma_f32_16x16x32_bf16(a, b, acc[n], 0, 0, 0);
      }
    }
    __syncthreads();
  }

  const int q4 = (lane >> 4) * 4, colb = lane & 15;
  #pragma unroll
  for (int n = 0; n < 8; n++) {
    int col = n0 + n * 16 + colb;
    #pragma unroll
    for (int q = 0; q < 4; q++) {
      int row = m0 + (wave << 4) + q4 + q;
      unsafeAtomicAdd(&SPEC[(size_t)row * C + col], acc[n][q]);
    }
  }
}

// =====================================================================
// smallprep: S = exp(-evals*max(dt,1e-8))*SPEC; outputs bf16 TRANSPOSED
// St/Trt/Tit [CO][128] (Tr=S@Are, Ti=S@Aim) and SWt = (S@w0b)^T [CO][128]
// =====================================================================
template<int C>
__global__ void k_smallprep(const float* __restrict__ SPEC, const float* __restrict__ evals,
                            const float* __restrict__ dt, const float* __restrict__ Are,
                            const float* __restrict__ Aim, const float* __restrict__ w0,
                            u16* __restrict__ St, u16* __restrict__ Trt,
                            u16* __restrict__ Tit, u16* __restrict__ SWt)
{
  __shared__ float sld[C];
  const int k = blockIdx.x;
  const int c = threadIdx.x;
  const float ev = evals[k];
  float s = expf(-ev * fmaxf(dt[c], 1e-8f)) * SPEC[(size_t)k * C + c];
  sld[c] = s;
  St[(size_t)c * 128 + k] = f2bf(s);
  __syncthreads();
  float tr = 0.f, ti = 0.f, sw = 0.f;
  for (int j = 0; j < C; j++) {
    float sj = sld[j];
    tr = fmaf(sj, Are[(size_t)j * C + c], tr);
    ti = fmaf(sj, Aim[(size_t)j * C + c], ti);
    sw = fmaf(sj, w0[(size_t)(C + j) * C + c], sw);
  }
  Trt[(size_t)c * 128 + k] = f2bf(tr);
  Tit[(size_t)c * 128 + k] = f2bf(ti);
  SWt[(size_t)c * 128 + k] = f2bf(sw);
}

// ===== weight pre-transpose f32[K][N] -> bf16 Wt[N][K] (z batches) =====
__global__ void k_prepw(const float* __restrict__ W, u16* __restrict__ WT, int K, int N) {
  size_t zoff = (size_t)blockIdx.z * K * N;
  int i = blockIdx.x * 256 + threadIdx.x;
  if (i < K * N) {
    int k = i / N, n = i % N;
    WT[zoff + (size_t)n * K + k] = f2bf(W[zoff + i]);
  }
}

// ============================ CSR build ==============================
__global__ void k_hist(const int* __restrict__ idx, int* __restrict__ deg, int E) {
  int e = blockIdx.x * 256 + threadIdx.x;
  if (e < E) atomicAdd(&deg[idx[2 * e]], 1);
}
__global__ void k_scan1(const int* __restrict__ deg, int* __restrict__ excl,
                        int* __restrict__ bsum, int V) {
  __shared__ int sd[256];
  int t = threadIdx.x;
  int i = blockIdx.x * 256 + t;
  int v = (i < V) ? deg[i] : 0;
  sd[t] = v;
  __syncthreads();
  for (int off = 1; off < 256; off <<= 1) {
    int add = (t >= off) ? sd[t - off] : 0;
    __syncthreads();
    sd[t] += add;
    __syncthreads();
  }
  if (i < V) excl[i] = sd[t] - v;
  if (t == 255) bsum[blockIdx.x] = sd[255];
}
__global__ void k_scan2(int* __restrict__ bsum, int nb, int* __restrict__ rowptr, int V) {
  __shared__ int sd[512];
  int t = threadIdx.x;
  int v = (t < nb) ? bsum[t] : 0;
  sd[t] = v;
  __syncthreads();
  for (int off = 1; off < 512; off <<= 1) {
    int add = (t >= off) ? sd[t - off] : 0;
    __syncthreads();
    sd[t] += add;
    __syncthreads();
  }
  if (t < nb) bsum[t] = sd[t] - v;
  if (t == 0) rowptr[V] = sd[511];
}
__global__ void k_scan3(const int* __restrict__ excl, const int* __restrict__ bsum,
                        int* __restrict__ rowptr, int V) {
  int i = blockIdx.x * 256 + threadIdx.x;
  if (i < V) rowptr[i] = excl[i] + bsum[i >> 8];
}
__global__ void k_scatter(const int* __restrict__ idx, const float* __restrict__ val,
                          const int* __restrict__ rowptr, int* __restrict__ cur,
                          int* __restrict__ ecol, float* __restrict__ eval, int E) {
  int e = blockIdx.x * 256 + threadIdx.x;
  if (e < E) {
    int d = idx[2 * e];
    int p = rowptr[d] + atomicAdd(&cur[d], 1);
    ecol[p] = idx[2 * e + 1];
    eval[p] = val[e];
  }
}
__global__ __launch_bounds__(256)
void k_spmm_csr(const int* __restrict__ rowptr, const int* __restrict__ ecol,
                const float* __restrict__ eval, const float* __restrict__ E,
                u16* __restrict__ GE, int V) {
  int r = blockIdx.x * 8 + (threadIdx.x >> 5);
  int lane = threadIdx.x & 31;
  if (r >= V) return;
  int j1 = rowptr[r + 1];
  float4 a = make_float4(0.f,0.f,0.f,0.f);
  for (int j = rowptr[r]; j < j1; j++) {
    int c = ecol[j];
    float v = eval[j];
    float4 x = ld4(E + (size_t)c * KE + lane * 4);
    a.x = fmaf(v, x.x, a.x); a.y = fmaf(v, x.y, a.y);
    a.z = fmaf(v, x.z, a.z); a.w = fmaf(v, x.w, a.w);
  }
  ushort4 o;
  o.x = f2bf(a.x); o.y = f2bf(a.y); o.z = f2bf(a.z); o.w = f2bf(a.w);
  *(ushort4*)(GE + (size_t)r * KE + lane * 4) = o;
}

// ============================ segment max ============================
__global__ void k_segmax_init(unsigned* __restrict__ u, int n) {
  int i = blockIdx.x * 256 + threadIdx.x;
  if (i < n) u[i] = 0x007FFFFFu;
}
__global__ void k_segmax_scatter(const float* __restrict__ X, const int* __restrict__ tr,
                                 unsigned* __restrict__ u) {
  int i = blockIdx.x * 256 + threadIdx.x;
  if (i >= V3 * C3) return;
  int v = i >> 7, c = i & 127;
  unsigned b = __float_as_uint(X[i]);
  unsigned m = (b & 0x80000000u) ? ~b : (b | 0x80000000u);
  atomicMax(&u[((size_t)tr[v] << 7) + c], m);
}
__global__ void k_segmax_decode(const unsigned* __restrict__ u, float* __restrict__ out, int n) {
  int i = blockIdx.x * 256 + threadIdx.x;
  if (i < n) {
    unsigned m = u[i];
    float f = 0.f;
    if (m != 0x007FFFFFu) {
      unsigned b = (m & 0x80000000u) ? (m & 0x7FFFFFFFu) : ~m;
      f = __uint_as_float(b);
    }
    out[i] = f;
  }
}

// ========================= final projection ==========================
__global__ __launch_bounds__(256)
void k_outproj(const float* __restrict__ Y, const float* __restrict__ W,
               const float* __restrict__ B, float* __restrict__ OUT, int V) {
  __shared__ float Wl[128][22];
  __shared__ float ys[8][128];
  const int tid = threadIdx.x;
  for (int f = tid; f < 128 * 21; f += 256) Wl[f / 21][f % 21] = W[f];
  {
    int r = tid >> 5, cc = (tid & 31) * 4;
    int v = blockIdx.x * 8 + r;
    float4 yv = make_float4(0.f,0.f,0.f,0.f);
    if (v < V) yv = ld4(Y + (size_t)v * C3 + cc);
    st4(&ys[r][cc], yv);
  }
  __syncthreads();
  int r = tid >> 5, c = tid & 31;
  int v = blockIdx.x * 8 + r;
  if (v < V && c < 21) {
    float acc = B[c];
    #pragma unroll 8
    for (int k = 0; k < 128; k++) acc = fmaf(ys[r][k], Wl[k][c], acc);
    OUT[(size_t)v * 21 + c] = acc;
  }
}

// =====================================================================
extern "C" void kernel_launch(void* const* d_in, const int* in_sizes, int n_in,
                              void* d_out, int out_size, void* d_ws, size_t ws_size,
                              hipStream_t stream)
{
  (void)in_sizes; (void)n_in; (void)out_size;
  const float* x_in    = (const float*)d_in[0];
  const float* mass3   = (const float*)d_in[1];
  const float* evals3  = (const float*)d_in[2];
  const float* evecs3  = (const float*)d_in[3];
  const int*   gX3i    = (const int*)d_in[4];
  const float* gX3v    = (const float*)d_in[5];
  const int*   gY3i    = (const int*)d_in[6];
  const float* gY3v    = (const float*)d_in[7];
  const float* massm   = (const float*)d_in[8];
  const float* evalsm  = (const float*)d_in[9];
  const float* evecsm  = (const float*)d_in[10];
  const int*   gXmi    = (const int*)d_in[11];
  const float* gXmv    = (const float*)d_in[12];
  const int*   gYmi    = (const int*)d_in[13];
  const float* gYmv    = (const float*)d_in[14];
  const int*   tr34    = (const int*)d_in[15];
  const float* in_w    = (const float*)d_in[16];
  const float* in_b    = (const float*)d_in[17];
  const float* widen_w = (const float*)d_in[18];
  const float* widen_b = (const float*)d_in[19];
  const float* narrow_w= (const float*)d_in[20];
  const float* narrow_b= (const float*)d_in[21];
  const float* halve_w = (const float*)d_in[22];
  const float* halve_b = (const float*)d_in[23];
  const float* out_w   = (const float*)d_in[24];
  const float* out_b   = (const float*)d_in[25];
  const float* enc_p[9]; const float* mid_p[9]; const float* dec_p[9];
  for (int i = 0; i < 9; i++) {
    enc_p[i] = (const float*)d_in[26 + i];
    mid_p[i] = (const float*)d_in[35 + i];
    dec_p[i] = (const float*)d_in[44 + i];
  }

  // ---------------- workspace layout (~195 MB) ----------------
  char* ws = (char*)d_ws;
  const size_t B3 = (size_t)V3 * C3 * 4;            // 51,200,000
  size_t off = 0;
  float* SA = (float*)(ws + off); off += B3;
  float* SB = (float*)(ws + off); off += B3;
  u16* GEX3 = (u16*)(ws + off); off += (size_t)V3 * KE * 2;
  u16* GEY3 = (u16*)(ws + off); off += (size_t)V3 * KE * 2;
  u16* GEXm = (u16*)(ws + off); off += (size_t)VM * KE * 2;
  u16* GEYm = (u16*)(ws + off); off += (size_t)VM * KE * 2;
  u16* BSCR = (u16*)(ws + off); off += (size_t)V3 * C3 * 2;  // 25.6MB bf16 scratch
  float* spec = (float*)(ws + off); off += 131072;
  u16* St  = (u16*)(ws + off); off += 65536;
  u16* Trt = (u16*)(ws + off); off += 65536;
  u16* Tit = (u16*)(ws + off); off += 65536;
  u16* SWt = (u16*)(ws + off); off += 65536;
  u16* wT  = (u16*)(ws + off); off += 2400000;
  int* bsum = (int*)(ws + off); off += 4096;
  const size_t NEED = off;
  if (ws_size < NEED) return;

  // CSR scratch overlays SA (dead before in_proj)
  int*   rowptr = (int*)SA;
  int*   deg    = (int*)((char*)SA + 400128);
  int*   ecol   = (int*)((char*)SA + 800256);
  float* evalv  = (float*)((char*)SA + 4000256);

  // mid-phase overlay inside SB (x3 lives in SA then)
  unsigned* xm_u  = (unsigned*)((char*)SB);
  float*    xm_dec= (float*)((char*)SB + 12800000);
  float*    m0    = (float*)((char*)SB + 25600000);   // VM*256 f32
  float*    m1    = (float*)((char*)SB);              // after xm dead
  u16* BSCR0 = BSCR;
  u16* BSCR1 = BSCR + (size_t)VM * CMID;              // +12.8MB (mid H1)

  // weight-transpose suballocation (element offsets)
  u16* in_wt    = wT + 0;
  u16* widen_t  = wT + 2048;
  u16* narrow_t = wT + 34816;
  u16* halve_t  = wT + 67584;
  u16* enc_w0t  = wT + 100352;   // 2 x [128][384]
  u16* enc_w1t  = wT + 198656;
  u16* enc_w2t  = wT + 231424;
  u16* mid_w0t  = wT + 264192;   // 2 x [256][768]
  u16* mid_w1t  = wT + 657408;
  u16* mid_w2t  = wT + 788480;
  u16* dec_w0t  = wT + 919552;
  u16* dec_w1t  = wT + 1017856;
  u16* dec_w2t  = wT + 1050624;

  // ---- weight pre-transpose + bf16 ----
  auto prepw = [&](const float* W, u16* WT, int K, int N, int z) {
    k_prepw<<<dim3(cdiv(K * N, 256), 1, z), 256, 0, stream>>>(W, WT, K, N);
  };
  prepw(in_w, in_wt, 16, 128, 1);
  prepw(widen_w, widen_t, 128, 256, 1);
  prepw(narrow_w, narrow_t, 256, 128, 1);
  prepw(halve_w, halve_t, 256, 128, 1);
  prepw(enc_p[3], enc_w0t, 384, 128, 2);
  prepw(enc_p[5], enc_w1t, 128, 128, 2);
  prepw(enc_p[7], enc_w2t, 128, 128, 2);
  prepw(mid_p[3], mid_w0t, 768, 256, 2);
  prepw(mid_p[5], mid_w1t, 256, 256, 2);
  prepw(mid_p[7], mid_w2t, 256, 256, 2);
  prepw(dec_p[3], dec_w0t, 384, 128, 2);
  prepw(dec_p[5], dec_w1t, 128, 128, 2);
  prepw(dec_p[7], dec_w2t, 128, 128, 2);

  // ---- GE = G @ evecs (bf16) ----
  auto build_ge = [&](const int* idx, const float* val, int E_, int V_,
                      const float* Evec, u16* GE) {
    hipMemsetAsync(deg, 0, (size_t)V_ * 4, stream);
    k_hist<<<cdiv(E_, 256), 256, 0, stream>>>(idx, deg, E_);
    int nb = cdiv(V_, 256);
    k_scan1<<<nb, 256, 0, stream>>>(deg, ecol, bsum, V_);
    k_scan2<<<1, 512, 0, stream>>>(bsum, nb, rowptr, V_);
    k_scan3<<<nb, 256, 0, stream>>>(ecol, bsum, rowptr, V_);
    hipMemsetAsync(deg, 0, (size_t)V_ * 4, stream);
    k_scatter<<<cdiv(E_, 256), 256, 0, stream>>>(idx, val, rowptr, deg, ecol, evalv, E_);
    k_spmm_csr<<<cdiv(V_, 8), 256, 0, stream>>>(rowptr, ecol, evalv, Evec, GE, V_);
  };
  build_ge(gX3i, gX3v, E3, V3, evecs3, GEX3);
  build_ge(gY3i, gY3v, E3, V3, evecs3, GEY3);
  build_ge(gXmi, gXmv, EM, VM, evecsm, GEXm);
  build_ge(gYmi, gYmv, EM, VM, evecsm, GEYm);

  const int G3 = cdiv(V3, 64);   // 1563
  const int GM = cdiv(VM, 64);   // 391

  // ---- block runners ----
  auto run_block3 = [&](const float* X, float* OX, const float* p[9],
                        const u16* w0t, const u16* w1t, const u16* w2t, int i) {
    const float* dt  = p[0] + (size_t)i * C3;
    const float* Are = p[1] + (size_t)i * C3 * C3;
    const float* Aim = p[2] + (size_t)i * C3 * C3;
    const float* w0  = p[3] + (size_t)i * 3 * C3 * C3;
    const float* b0  = p[4] + (size_t)i * C3;
    const float* b1  = p[6] + (size_t)i * C3;
    const float* b2  = p[8] + (size_t)i * C3;
    const u16* w0ti = w0t + (size_t)i * 3 * C3 * C3;
    const u16* w1ti = w1t + (size_t)i * C3 * C3;
    const u16* w2ti = w2t + (size_t)i * C3 * C3;
    hipMemsetAsync(spec, 0, (size_t)KE * C3 * 4, stream);
    k_specmm<<<dim3(cdiv(V3, 512), 2, 1), 256, 0, stream>>>(evecs3, X, mass3, spec, C3, V3, 512);
    k_smallprep<C3><<<KE, C3, 0, stream>>>(spec, evals3, dt, Are, Aim, w0, St, Trt, Tit, SWt);
    k_mgate<<<dim3(G3, 2), 256, 0, stream>>>(GEX3, GEY3, St, Trt, Tit, BSCR, C3, V3);
    k_mgemm<true,false,false,true><<<dim3(G3, 1), 256, 0, stream>>>(
        X, 0, C3, w0ti, 3*C3, 0,
        BSCR, 1, C3, w0ti, 3*C3, 2*C3,
        evecs3, 0, KE, SWt, 128, 0,
        nullptr, b0, nullptr, BSCR, C3, V3);              // H1 in-place over GF
    k_mgemm<true,false,false,true><<<dim3(G3, 1), 256, 0, stream>>>(
        BSCR, 1, C3, w1ti, C3, 0,
        nullptr,0,0,nullptr,0,0, nullptr,0,0,nullptr,0,0,
        nullptr, b1, nullptr, BSCR, C3, V3);              // H2 in-place
    k_mgemm<false,true,false,false><<<dim3(G3, 1), 256, 0, stream>>>(
        BSCR, 1, C3, w2ti, C3, 0,
        nullptr,0,0,nullptr,0,0, nullptr,0,0,nullptr,0,0,
        nullptr, b2, X, OX, C3, V3);
  };
  auto run_blockm = [&](const float* X, float* OX, const float* p[9],
                        const u16* w0t, const u16* w1t, const u16* w2t, int i) {
    const float* dt  = p[0] + (size_t)i * CMID;
    const float* Are = p[1] + (size_t)i * CMID * CMID;
    const float* Aim = p[2] + (size_t)i * CMID * CMID;
    const float* w0  = p[3] + (size_t)i * 3 * CMID * CMID;
    const float* b0  = p[4] + (size_t)i * CMID;
    const float* b1  = p[6] + (size_t)i * CMID;
    const float* b2  = p[8] + (size_t)i * CMID;
    const u16* w0ti = w0t + (size_t)i * 3 * CMID * CMID;
    const u16* w1ti = w1t + (size_t)i * CMID * CMID;
    const u16* w2ti = w2t + (size_t)i * CMID * CMID;
    hipMemsetAsync(spec, 0, (size_t)KE * CMID * 4, stream);
    k_specmm<<<dim3(cdiv(VM, 256), 2, 2), 256, 0, stream>>>(evecsm, X, massm, spec, CMID, VM, 256);
    k_smallprep<CMID><<<KE, CMID, 0, stream>>>(spec, evalsm, dt, Are, Aim, w0, St, Trt, Tit, SWt);
    k_mgate<<<dim3(GM, 4), 256, 0, stream>>>(GEXm, GEYm, St, Trt, Tit, BSCR0, CMID, VM);
    k_mgemm<true,false,false,true><<<dim3(GM, 2), 256, 0, stream>>>(
        X, 0, CMID, w0ti, 3*CMID, 0,
        BSCR0, 1, CMID, w0ti, 3*CMID, 2*CMID,
        evecsm, 0, KE, SWt, 128, 0,
        nullptr, b0, nullptr, BSCR1, CMID, VM);           // H1 (separate buf: y=2)
    k_mgemm<true,false,false,true><<<dim3(GM, 2), 256, 0, stream>>>(
        BSCR1, 1, CMID, w1ti, CMID, 0,
        nullptr,0,0,nullptr,0,0, nullptr,0,0,nullptr,0,0,
        nullptr, b1, nullptr, BSCR0, CMID, VM);           // H2 over GF (dead)
    k_mgemm<false,true,false,false><<<dim3(GM, 2), 256, 0, stream>>>(
        BSCR0, 1, CMID, w2ti, CMID, 0,
        nullptr,0,0,nullptr,0,0, nullptr,0,0,nullptr,0,0,
        nullptr, b2, X, OX, CMID, VM);
  };

  // ---- encoder ----
  k_mgemm<true,false,false,false><<<dim3(G3, 1), 256, 0, stream>>>(
      x_in, 0, 16, in_wt, 16, 0,
      nullptr,0,0,nullptr,0,0, nullptr,0,0,nullptr,0,0,
      nullptr, in_b, nullptr, SA, C3, V3);
  run_block3(SA, SB, enc_p, enc_w0t, enc_w1t, enc_w2t, 0);
  run_block3(SB, SA, enc_p, enc_w0t, enc_w1t, enc_w2t, 1);   // x3 = SA

  // ---- pool ----
  k_segmax_init<<<cdiv(VM * C3, 256), 256, 0, stream>>>(xm_u, VM * C3);
  k_segmax_scatter<<<cdiv(V3 * C3, 256), 256, 0, stream>>>(SA, tr34, xm_u);
  k_segmax_decode<<<cdiv(VM * C3, 256), 256, 0, stream>>>(xm_u, xm_dec, VM * C3);
  k_mgemm<true,false,false,false><<<dim3(GM, 2), 256, 0, stream>>>(
      xm_dec, 0, C3, widen_t, C3, 0,
      nullptr,0,0,nullptr,0,0, nullptr,0,0,nullptr,0,0,
      nullptr, widen_b, nullptr, m0, CMID, VM);
  run_blockm(m0, m1, mid_p, mid_w0t, mid_w1t, mid_w2t, 0);
  run_blockm(m1, m0, mid_p, mid_w0t, mid_w1t, mid_w2t, 1);   // m_final = m0

  // ---- unpool ----
  k_mgemm<true,false,true,true><<<dim3(G3, 1), 256, 0, stream>>>(
      m0, 0, CMID, narrow_t, CMID, 0,
      nullptr,0,0,nullptr,0,0, nullptr,0,0,nullptr,0,0,
      tr34, narrow_b, nullptr, BSCR, C3, V3);               // y_narrow bf16
  k_mgemm<true,false,false,false><<<dim3(G3, 1), 256, 0, stream>>>(
      BSCR, 1, C3, halve_t, 2*C3, 0,
      SA, 0, C3, halve_t, 2*C3, C3,
      nullptr,0,0,nullptr,0,0,
      nullptr, halve_b, nullptr, SB, C3, V3);

  // ---- decoder ----
  run_block3(SB, SA, dec_p, dec_w0t, dec_w1t, dec_w2t, 0);
  run_block3(SA, SB, dec_p, dec_w0t, dec_w1t, dec_w2t, 1);

  // ---- output projection ----
  k_outproj<<<cdiv(V3, 8), 256, 0, stream>>>(SB, out_w, out_b, (float*)d_out, V3);
}